// Round 1
// baseline (84.740 us; speedup 1.0000x reference)
//
#include <hip/hip_runtime.h>

// FFT convolution: out[c] = full linear conv of audio[c] with flip(rir).
// N = 2^18 >= 2T-1, so circular conv == linear conv on [0, 2T-2].
// Pack ch0+i*ch1, ch2+i*ch3 (real kernel => Re/Im separate convolutions).
// Radix-4 Stockham, 9 ping-pong passes, natural order in/out.

#define FFT_N 262144
#define FFT_LOG2N 18
#define NQ 65536   // FFT_N / 4

__device__ __forceinline__ float2 cadd(float2 a, float2 b) { return make_float2(a.x + b.x, a.y + b.y); }
__device__ __forceinline__ float2 csub(float2 a, float2 b) { return make_float2(a.x - b.x, a.y - b.y); }
__device__ __forceinline__ float2 cmul(float2 a, float2 b) {
    return make_float2(a.x * b.x - a.y * b.y, a.x * b.y + a.y * b.x);
}

__global__ void pack_kernel(const float* __restrict__ audio, const float* __restrict__ rir,
                            float2* __restrict__ dst, int T) {
    int n = blockIdx.x * blockDim.x + threadIdx.x;
    if (n >= FFT_N) return;
    float2 z1 = make_float2(0.f, 0.f), z2 = make_float2(0.f, 0.f), r = make_float2(0.f, 0.f);
    if (n < T) {
        z1 = make_float2(audio[n], audio[T + n]);
        z2 = make_float2(audio[2 * T + n], audio[3 * T + n]);
        r.x = rir[T - 1 - n];   // flipped rir (cross-correlation == conv with flip)
    }
    dst[n] = z1;
    dst[FFT_N + n] = z2;
    dst[2 * FFT_N + n] = r;
}

// One radix-4 Stockham pass. sign = -1 forward, +1 inverse.
// Pass t: s = 4^t. Read x[q + s*(p + i*m)], write y[q + s*(4p + i)], m = NQ/s.
__global__ void fft_pass_kernel(const float2* __restrict__ in, float2* __restrict__ out,
                                int log2s, float sign, int nbatch) {
    int tid = blockIdx.x * blockDim.x + threadIdx.x;
    if (tid >= nbatch * NQ) return;
    int b = tid >> 16;            // NQ == 2^16
    int j = tid & (NQ - 1);
    int s = 1 << log2s;
    int q = j & (s - 1);
    int p = j >> log2s;
    int base = b << FFT_LOG2N;

    int ri = base + q + s * p;
    float2 a  = in[ri];
    float2 bb = in[ri + NQ];
    float2 c  = in[ri + 2 * NQ];
    float2 d  = in[ri + 3 * NQ];

    float2 apc = cadd(a, c), amc = csub(a, c);
    float2 bpd = cadd(bb, d), bmd = csub(bb, d);
    float2 jb  = make_float2(-bmd.y, bmd.x);    // i*(b-d)

    // twiddle: w1 = exp(sign * i * 2*pi * s * p / N); s*p < 2^16 -> exact in fp32
    float ang = sign * 2.3968449808418217e-5f * (float)(s * p);
    float sn, cs;
    sincosf(ang, &sn, &cs);
    float2 w1 = make_float2(cs, sn);
    float2 w2 = cmul(w1, w1);
    float2 w3 = cmul(w2, w1);

    float2 y0 = cadd(apc, bpd);
    float2 t1 = make_float2(amc.x + sign * jb.x, amc.y + sign * jb.y);  // fwd: amc - jb
    float2 t2 = csub(apc, bpd);
    float2 t3 = make_float2(amc.x - sign * jb.x, amc.y - sign * jb.y);  // fwd: amc + jb

    int wi = base + q + (p << (log2s + 2));
    out[wi]         = y0;
    out[wi + s]     = cmul(w1, t1);
    out[wi + 2 * s] = cmul(w2, t2);
    out[wi + 3 * s] = cmul(w3, t3);
}

__global__ void pointwise_kernel(const float2* __restrict__ src, float2* __restrict__ dst) {
    int n = blockIdx.x * blockDim.x + threadIdx.x;
    if (n >= FFT_N) return;
    float2 z1 = src[n], z2 = src[FFT_N + n], r = src[2 * FFT_N + n];
    const float inv = 1.0f / (float)FFT_N;     // fused IFFT 1/N scale
    float2 y1 = cmul(z1, r);
    float2 y2 = cmul(z2, r);
    dst[n]         = make_float2(y1.x * inv, y1.y * inv);
    dst[FFT_N + n] = make_float2(y2.x * inv, y2.y * inv);
}

__global__ void unpack_kernel(const float2* __restrict__ src, float* __restrict__ out, int L) {
    int n = blockIdx.x * blockDim.x + threadIdx.x;
    if (n >= L) return;
    float2 y1 = src[n], y2 = src[FFT_N + n];
    out[n]         = y1.x;   // ch0
    out[L + n]     = y1.y;   // ch1
    out[2 * L + n] = y2.x;   // ch2
    out[3 * L + n] = y2.y;   // ch3
}

extern "C" void kernel_launch(void* const* d_in, const int* in_sizes, int n_in,
                              void* d_out, int out_size, void* d_ws, size_t ws_size,
                              hipStream_t stream) {
    const float* audio = (const float*)d_in[0];   // (1, 4, T) f32
    const float* rir   = (const float*)d_in[1];   // (T,) f32
    float* out = (float*)d_out;                   // (1, 4, 2T-1) f32
    int T = in_sizes[1];                          // 131072
    int L = out_size / 4;                         // 262143

    float2* bufA = (float2*)d_ws;                 // 3*N complex
    float2* bufB = bufA + 3 * FFT_N;              // 3*N complex (12.6 MB total)

    pack_kernel<<<FFT_N / 256, 256, 0, stream>>>(audio, rir, bufA, T);

    // forward FFT, batch 3 (z1, z2, rir): 9 radix-4 passes, A->B->A...->B
    float2* pin = bufA;
    float2* pout = bufB;
    for (int pass = 0; pass < 9; ++pass) {
        fft_pass_kernel<<<3 * NQ / 256, 256, 0, stream>>>(pin, pout, 2 * pass, -1.0f, 3);
        float2* t = pin; pin = pout; pout = t;
    }
    // result in pin (== bufB)

    pointwise_kernel<<<FFT_N / 256, 256, 0, stream>>>(pin, pout);

    // inverse FFT, batch 2: 9 radix-4 passes
    float2* qin = pout;
    float2* qout = pin;
    for (int pass = 0; pass < 9; ++pass) {
        fft_pass_kernel<<<2 * NQ / 256, 256, 0, stream>>>(qin, qout, 2 * pass, +1.0f, 2);
        float2* t = qin; qin = qout; qout = t;
    }
    // result in qin

    unpack_kernel<<<(L + 255) / 256, 256, 0, stream>>>(qin, out, L);
}

// Round 2
// 44.697 us; speedup vs baseline: 1.8959x; 1.8959x over previous
//
#include <hip/hip_runtime.h>

// Four-step FFT convolution, N = 2^18 = 512 x 512.
//   out[c] = full linear conv of audio[c] with flip(rir), length 2T-1.
// Pack: z1 = ch0 + i*ch1, z2 = ch2 + i*ch3 (rir real => Re/Im separate).
// K1: column FFT (n1) + twiddle, K2: row FFT + pointwise + row IFFT + twiddle,
// K3: column IFFT + unpack. Each 512-pt FFT done by one wave (64 lanes x 8 elems,
// 3 radix-8 Stockham stages, LDS exchange between stages).

#define NTOT 262144
#define TLEN 131072
#define PI2_N   2.3968449808418217e-5f   /* 2*pi / 262144 */
#define PI2_512 1.2271846303085129e-2f   /* 2*pi / 512    */
#define SIDX(i) ((i) + ((i) >> 3))       /* LDS pad: 4-way max conflicts */

__device__ __forceinline__ float2 cadd(float2 a, float2 b) { return make_float2(a.x + b.x, a.y + b.y); }
__device__ __forceinline__ float2 csub(float2 a, float2 b) { return make_float2(a.x - b.x, a.y - b.y); }
__device__ __forceinline__ float2 cmul(float2 a, float2 b) {
    return make_float2(a.x * b.x - a.y * b.y, a.x * b.y + a.y * b.x);
}

// 8-point DFT in registers. SIGN = -1 fwd, +1 inv.
template<int SIGN>
__device__ __forceinline__ void dft8(float2 x[8]) {
    const float R2 = 0.70710678118654752f;
    float2 t0 = cadd(x[0], x[4]), t1 = csub(x[0], x[4]);
    float2 t2 = cadd(x[2], x[6]), t3 = csub(x[2], x[6]);
    float2 u0 = cadd(x[1], x[5]), u1 = csub(x[1], x[5]);
    float2 u2 = cadd(x[3], x[7]), u3 = csub(x[3], x[7]);
    // rot(z) = SIGN*i*z
    float2 it3 = (SIGN > 0) ? make_float2(-t3.y, t3.x) : make_float2(t3.y, -t3.x);
    float2 iu3 = (SIGN > 0) ? make_float2(-u3.y, u3.x) : make_float2(u3.y, -u3.x);
    float2 E0 = cadd(t0, t2), E2 = csub(t0, t2);
    float2 E1 = cadd(t1, it3), E3 = csub(t1, it3);
    float2 O0 = cadd(u0, u2), O2 = csub(u0, u2);
    float2 O1 = cadd(u1, iu3), O3 = csub(u1, iu3);
    float2 iO2 = (SIGN > 0) ? make_float2(-O2.y, O2.x) : make_float2(O2.y, -O2.x);
    float2 w1O1 = (SIGN > 0) ? make_float2(R2 * (O1.x - O1.y), R2 * (O1.y + O1.x))
                             : make_float2(R2 * (O1.x + O1.y), R2 * (O1.y - O1.x));
    float2 w3O3 = (SIGN > 0) ? make_float2(R2 * (-O3.x - O3.y), R2 * (O3.x - O3.y))
                             : make_float2(R2 * (O3.y - O3.x), R2 * (-O3.x - O3.y));
    x[0] = cadd(E0, O0);   x[4] = csub(E0, O0);
    x[1] = cadd(E1, w1O1); x[5] = csub(E1, w1O1);
    x[2] = cadd(E2, iO2);  x[6] = csub(E2, iO2);
    x[3] = cadd(E3, w3O3); x[7] = csub(E3, w3O3);
}

// x[i] *= exp(SIGN * i_img * baseAng * i), baseAng >= 0
template<int SIGN>
__device__ __forceinline__ void twiddle8(float2 x[8], float baseAng) {
    float sn, cs;
    sincosf((SIGN < 0) ? -baseAng : baseAng, &sn, &cs);
    float2 w = make_float2(cs, sn), wp = w;
    x[1] = cmul(x[1], wp);
#pragma unroll
    for (int i = 2; i < 8; ++i) { wp = cmul(wp, w); x[i] = cmul(x[i], wp); }
}

// 512-pt FFT across one wave. In/out: x[i] = data[lane + 64*i]. lds: 576 float2, wave-private.
template<int SIGN>
__device__ void fft512_wave(float2 x[8], int lane, float2* lds) {
    // pass 0: s=1, p=lane
    dft8<SIGN>(x);
    twiddle8<SIGN>(x, PI2_512 * (float)lane);
#pragma unroll
    for (int i = 0; i < 8; ++i) lds[SIDX(8 * lane + i)] = x[i];
    __syncthreads();
    int q = lane & 7, p = lane >> 3;
#pragma unroll
    for (int i = 0; i < 8; ++i) x[i] = lds[SIDX(q + 8 * p + 64 * i)];
    // pass 1: s=8
    dft8<SIGN>(x);
    twiddle8<SIGN>(x, PI2_512 * (float)(8 * p));
    __syncthreads();
#pragma unroll
    for (int i = 0; i < 8; ++i) lds[SIDX(q + 64 * p + 8 * i)] = x[i];
    __syncthreads();
#pragma unroll
    for (int i = 0; i < 8; ++i) x[i] = lds[SIDX(lane + 64 * i)];
    // pass 2: s=64, p=0 -> no twiddle
    dft8<SIGN>(x);
}

// K1: column FFT over n1 for each (seq, n2). Input n = 512*n1 + n2; nonzero only n1 < 256.
// Writes S[seq][n2][k1] (k1 fast, coalesced), with twiddle exp(-2pi*i*n2*k1/N).
__global__ void __launch_bounds__(256) k1_cols(const float* __restrict__ audio,
                                               const float* __restrict__ rir,
                                               float2* __restrict__ S) {
    int wid = threadIdx.x >> 6;
    int lane = threadIdx.x & 63;
    int gw = blockIdx.x * 4 + wid;
    int seq = gw >> 9;
    int n2 = gw & 511;
    __shared__ float2 lds[4 * 576];
    float2* mylds = lds + wid * 576;

    float2 x[8];
#pragma unroll
    for (int i = 0; i < 4; ++i) {
        int n = ((lane + 64 * i) << 9) | n2;   // < TLEN by construction
        if (seq == 0)      x[i] = make_float2(audio[n], audio[TLEN + n]);
        else if (seq == 1) x[i] = make_float2(audio[2 * TLEN + n], audio[3 * TLEN + n]);
        else               x[i] = make_float2(rir[TLEN - 1 - n], 0.f);
    }
#pragma unroll
    for (int i = 4; i < 8; ++i) x[i] = make_float2(0.f, 0.f);

    fft512_wave<-1>(x, lane, mylds);

    // twiddle chain: w(i) = exp(-2pi*i_img*n2*(lane+64i)/N)
    float sn0, cs0, sns, css;
    sincosf(-PI2_N * (float)(n2 * lane), &sn0, &cs0);
    sincosf(-PI2_N * (float)(n2 * 64), &sns, &css);
    float2 w = make_float2(cs0, sn0), ws = make_float2(css, sns);
    float2* dst = S + (size_t)seq * NTOT + (size_t)n2 * 512 + lane;
#pragma unroll
    for (int i = 0; i < 8; ++i) {
        dst[64 * i] = cmul(x[i], w);
        w = cmul(w, ws);
    }
}

// K2: per k1-row: fwd FFT (r, z1, z2) over n2, pointwise * (1/N), inv FFT over k2,
// twiddle exp(+2pi*i*n2*k1/N), write D[seq][k1][n2] (n2 fast, coalesced).
__global__ void __launch_bounds__(64) k2_rows(const float2* __restrict__ S,
                                              float2* __restrict__ D) {
    int k1 = blockIdx.x;
    int lane = threadIdx.x;
    __shared__ float2 lds[576];

    float2 zr[8], z1[8], z2[8];
#pragma unroll
    for (int i = 0; i < 8; ++i) {
        size_t a = (size_t)(lane + 64 * i) * 512 + k1;
        z1[i] = S[a];
        z2[i] = S[NTOT + a];
        zr[i] = S[2 * NTOT + a];
    }

    fft512_wave<-1>(zr, lane, lds);
    fft512_wave<-1>(z1, lane, lds);

    const float invN = 3.814697265625e-6f;  // 1/262144
#pragma unroll
    for (int i = 0; i < 8; ++i) {
        float2 yv = cmul(z1[i], zr[i]);
        z1[i] = make_float2(yv.x * invN, yv.y * invN);
    }
    fft512_wave<1>(z1, lane, lds);

    fft512_wave<-1>(z2, lane, lds);
#pragma unroll
    for (int i = 0; i < 8; ++i) {
        float2 yv = cmul(z2[i], zr[i]);
        z2[i] = make_float2(yv.x * invN, yv.y * invN);
    }
    fft512_wave<1>(z2, lane, lds);

    // inverse four-step twiddle + coalesced store
    float sn0, cs0, sns, css;
    sincosf(PI2_N * (float)(k1 * lane), &sn0, &cs0);
    sincosf(PI2_N * (float)(k1 * 64), &sns, &css);
    float2 w = make_float2(cs0, sn0), ws = make_float2(css, sns);
    float2* d1 = D + (size_t)k1 * 512 + lane;
    float2* d2 = d1 + NTOT;
#pragma unroll
    for (int i = 0; i < 8; ++i) {
        d1[64 * i] = cmul(z1[i], w);
        d2[64 * i] = cmul(z2[i], w);
        w = cmul(w, ws);
    }
}

// K3: inverse column FFT over k1 for each (seq, n2); unpack to 4 channels.
__global__ void __launch_bounds__(64) k3_cols(const float2* __restrict__ D,
                                              float* __restrict__ out, int L) {
    int gw = blockIdx.x;
    int seq = gw >> 9;
    int n2 = gw & 511;
    int lane = threadIdx.x;
    __shared__ float2 lds[576];

    float2 x[8];
    const float2* src = D + (size_t)seq * NTOT + n2 + lane * 512;
#pragma unroll
    for (int i = 0; i < 8; ++i) x[i] = src[64 * 512 * i];

    fft512_wave<1>(x, lane, lds);

    float* o0 = out + (size_t)(2 * seq) * L;
    float* o1 = out + (size_t)(2 * seq + 1) * L;
#pragma unroll
    for (int i = 0; i < 8; ++i) {
        int n = ((lane + 64 * i) << 9) | n2;
        if (n < L) { o0[n] = x[i].x; o1[n] = x[i].y; }
    }
}

extern "C" void kernel_launch(void* const* d_in, const int* in_sizes, int n_in,
                              void* d_out, int out_size, void* d_ws, size_t ws_size,
                              hipStream_t stream) {
    const float* audio = (const float*)d_in[0];   // (1, 4, T) f32
    const float* rir   = (const float*)d_in[1];   // (T,) f32
    float* out = (float*)d_out;                   // (1, 4, 2T-1) f32
    int L = out_size / 4;                         // 262143

    float2* S = (float2*)d_ws;        // 3*N complex
    float2* D = S + 3 * NTOT;         // 2*N complex (10.5 MB total)

    k1_cols<<<384, 256, 0, stream>>>(audio, rir, S);
    k2_rows<<<512, 64, 0, stream>>>(S, D);
    k3_cols<<<1024, 64, 0, stream>>>(D, out, L);
}

// Round 3
// 32.080 us; speedup vs baseline: 2.6415x; 1.3933x over previous
//
#include <hip/hip_runtime.h>

// Four-step FFT convolution, N = 2^18 = 512 x 512.
// K1: column FFT (n1) + twiddle  -> S[seq][n2][k1]
// K2: 3 waves/block: fwd row FFTs (r, z1, z2) || pointwise*1/N || inv row FFTs -> D[seq][k1][k2]
// K3: column IFFT over k1 + LDS transpose + coalesced unpack to 4 channels.
// All per-wave LDS exchanges use wave-local sync (no block barriers).

#define NTOT 262144
#define TLEN 131072
#define PI2_N   2.3968449808418217e-5f   /* 2*pi / 262144 */
#define PI2_512 1.2271846303085129e-2f   /* 2*pi / 512    */
#define SIDX(i) ((i) + ((i) >> 3))

__device__ __forceinline__ float2 cadd(float2 a, float2 b) { return make_float2(a.x + b.x, a.y + b.y); }
__device__ __forceinline__ float2 csub(float2 a, float2 b) { return make_float2(a.x - b.x, a.y - b.y); }
__device__ __forceinline__ float2 cmul(float2 a, float2 b) {
    return make_float2(a.x * b.x - a.y * b.y, a.x * b.y + a.y * b.x);
}
__device__ __forceinline__ float2 cexp_(float ang) {   // (cos, sin) via HW transcendentals
    float s, c;
    __sincosf(ang, &s, &c);
    return make_float2(c, s);
}
__device__ __forceinline__ void wsync() {              // wave-local LDS ordering
    asm volatile("s_waitcnt lgkmcnt(0)" ::: "memory");
    __builtin_amdgcn_sched_barrier(0);
}

template<int SIGN>
__device__ __forceinline__ void dft8(float2 x[8]) {
    const float R2 = 0.70710678118654752f;
    float2 t0 = cadd(x[0], x[4]), t1 = csub(x[0], x[4]);
    float2 t2 = cadd(x[2], x[6]), t3 = csub(x[2], x[6]);
    float2 u0 = cadd(x[1], x[5]), u1 = csub(x[1], x[5]);
    float2 u2 = cadd(x[3], x[7]), u3 = csub(x[3], x[7]);
    float2 it3 = (SIGN > 0) ? make_float2(-t3.y, t3.x) : make_float2(t3.y, -t3.x);
    float2 iu3 = (SIGN > 0) ? make_float2(-u3.y, u3.x) : make_float2(u3.y, -u3.x);
    float2 E0 = cadd(t0, t2), E2 = csub(t0, t2);
    float2 E1 = cadd(t1, it3), E3 = csub(t1, it3);
    float2 O0 = cadd(u0, u2), O2 = csub(u0, u2);
    float2 O1 = cadd(u1, iu3), O3 = csub(u1, iu3);
    float2 iO2 = (SIGN > 0) ? make_float2(-O2.y, O2.x) : make_float2(O2.y, -O2.x);
    float2 w1O1 = (SIGN > 0) ? make_float2(R2 * (O1.x - O1.y), R2 * (O1.y + O1.x))
                             : make_float2(R2 * (O1.x + O1.y), R2 * (O1.y - O1.x));
    float2 w3O3 = (SIGN > 0) ? make_float2(R2 * (-O3.x - O3.y), R2 * (O3.x - O3.y))
                             : make_float2(R2 * (O3.y - O3.x), R2 * (-O3.x - O3.y));
    x[0] = cadd(E0, O0);   x[4] = csub(E0, O0);
    x[1] = cadd(E1, w1O1); x[5] = csub(E1, w1O1);
    x[2] = cadd(E2, iO2);  x[6] = csub(E2, iO2);
    x[3] = cadd(E3, w3O3); x[7] = csub(E3, w3O3);
}

// dft8 specialized for x[4..7] == 0 (zero-padded half in K1)
template<int SIGN>
__device__ __forceinline__ void dft8z(float2 x[8]) {
    const float R2 = 0.70710678118654752f;
    float2 x0 = x[0], x1 = x[1], x2 = x[2], x3 = x[3];
    float2 rx2 = (SIGN > 0) ? make_float2(-x2.y, x2.x) : make_float2(x2.y, -x2.x);
    float2 rx3 = (SIGN > 0) ? make_float2(-x3.y, x3.x) : make_float2(x3.y, -x3.x);
    float2 E0 = cadd(x0, x2), E2 = csub(x0, x2);
    float2 E1 = cadd(x0, rx2), E3 = csub(x0, rx2);
    float2 O0 = cadd(x1, x3), O2 = csub(x1, x3);
    float2 O1 = cadd(x1, rx3), O3 = csub(x1, rx3);
    float2 iO2 = (SIGN > 0) ? make_float2(-O2.y, O2.x) : make_float2(O2.y, -O2.x);
    float2 w1O1 = (SIGN > 0) ? make_float2(R2 * (O1.x - O1.y), R2 * (O1.y + O1.x))
                             : make_float2(R2 * (O1.x + O1.y), R2 * (O1.y - O1.x));
    float2 w3O3 = (SIGN > 0) ? make_float2(R2 * (-O3.x - O3.y), R2 * (O3.x - O3.y))
                             : make_float2(R2 * (O3.y - O3.x), R2 * (-O3.x - O3.y));
    x[0] = cadd(E0, O0);   x[4] = csub(E0, O0);
    x[1] = cadd(E1, w1O1); x[5] = csub(E1, w1O1);
    x[2] = cadd(E2, iO2);  x[6] = csub(E2, iO2);
    x[3] = cadd(E3, w3O3); x[7] = csub(E3, w3O3);
}

template<int SIGN>
__device__ __forceinline__ void twiddle8i(float2 x[8], int base) {
#pragma unroll
    for (int i = 1; i < 8; ++i) {
        float ang = PI2_512 * (float)(base * i);      // exact int product
        x[i] = cmul(x[i], cexp_((SIGN < 0) ? -ang : ang));
    }
}

// 512-pt FFT on one wave: x[i] = data[lane + 64*i] in and out. lds: 576 float2, wave-private.
template<int SIGN, bool HZ = false>
__device__ void fft512_wave(float2 x[8], int lane, float2* lds) {
    wsync();                               // WAR vs prior reads of this buffer
    if (HZ) dft8z<SIGN>(x); else dft8<SIGN>(x);
    twiddle8i<SIGN>(x, lane);
#pragma unroll
    for (int i = 0; i < 8; ++i) lds[SIDX(8 * lane + i)] = x[i];
    wsync();
    int q = lane & 7, p = lane >> 3;
#pragma unroll
    for (int i = 0; i < 8; ++i) x[i] = lds[SIDX(q + 8 * p + 64 * i)];
    dft8<SIGN>(x);
    twiddle8i<SIGN>(x, 8 * p);
    wsync();                               // WAR before overwrite
#pragma unroll
    for (int i = 0; i < 8; ++i) lds[SIDX(q + 64 * p + 8 * i)] = x[i];
    wsync();
#pragma unroll
    for (int i = 0; i < 8; ++i) x[i] = lds[SIDX(lane + 64 * i)];
    dft8<SIGN>(x);
}

__global__ void __launch_bounds__(256) k1_cols(const float* __restrict__ audio,
                                               const float* __restrict__ rir,
                                               float2* __restrict__ S) {
    int wid = threadIdx.x >> 6, lane = threadIdx.x & 63;
    int gw = blockIdx.x * 4 + wid;
    int seq = gw >> 9, n2 = gw & 511;
    __shared__ float2 lds[4][576];

    float2 x[8];
#pragma unroll
    for (int i = 0; i < 4; ++i) {
        int n = ((lane + 64 * i) << 9) | n2;          // < TLEN
        if (seq == 0)      x[i] = make_float2(audio[n], audio[TLEN + n]);
        else if (seq == 1) x[i] = make_float2(audio[2 * TLEN + n], audio[3 * TLEN + n]);
        else               x[i] = make_float2(rir[TLEN - 1 - n], 0.f);
    }
#pragma unroll
    for (int i = 4; i < 8; ++i) x[i] = make_float2(0.f, 0.f);

    fft512_wave<-1, true>(x, lane, lds[wid]);

    float2* dst = S + (size_t)seq * NTOT + (size_t)n2 * 512 + lane;
#pragma unroll
    for (int i = 0; i < 8; ++i)
        dst[64 * i] = cmul(x[i], cexp_(-PI2_N * (float)(n2 * (lane + 64 * i))));
}

__global__ void __launch_bounds__(192) k2_rows(const float2* __restrict__ S,
                                               float2* __restrict__ D) {
    int wid = threadIdx.x >> 6, lane = threadIdx.x & 63;
    int k1 = blockIdx.x;
    __shared__ float2 scratch[3][576];
    __shared__ float2 Rspec[512];
    __shared__ float2 Wtw[512];

    const float2* src = S + (size_t)((wid == 0) ? 2 : (wid - 1)) * NTOT + k1;
    float2 z[8];
#pragma unroll
    for (int i = 0; i < 8; ++i) z[i] = src[(size_t)(lane + 64 * i) * 512];

    fft512_wave<-1>(z, lane, scratch[wid]);

    if (wid == 0) {
        const float invN = 3.814697265625e-6f;        // 1/262144
#pragma unroll
        for (int i = 0; i < 8; ++i)
            Rspec[lane + 64 * i] = make_float2(z[i].x * invN, z[i].y * invN);
#pragma unroll
        for (int i = 0; i < 8; ++i)
            Wtw[lane + 64 * i] = cexp_(PI2_N * (float)(k1 * (lane + 64 * i)));
    }
    __syncthreads();

    if (wid != 0) {
#pragma unroll
        for (int i = 0; i < 8; ++i) z[i] = cmul(z[i], Rspec[lane + 64 * i]);
        fft512_wave<1>(z, lane, scratch[wid]);
        float2* dst = D + (size_t)(wid - 1) * NTOT + (size_t)k1 * 512 + lane;
#pragma unroll
        for (int i = 0; i < 8; ++i)
            dst[64 * i] = cmul(z[i], Wtw[lane + 64 * i]);
    }
}

__global__ void __launch_bounds__(256) k3_cols(const float2* __restrict__ D,
                                               float* __restrict__ out, int L) {
    int wid = threadIdx.x >> 6, lane = threadIdx.x & 63;
    int bid = blockIdx.x;
    int gw4 = (bid & 7) * 32 + (bid >> 3);            // XCD swizzle (256 = 8*32, bijective)
    int seq = gw4 >> 7;
    int n2b = (gw4 & 127) * 4;
    __shared__ float2 scratch[4][576];
    __shared__ float tile[2][4][512];

    const float2* src = D + (size_t)seq * NTOT + (n2b + wid);
    float2 x[8];
#pragma unroll
    for (int i = 0; i < 8; ++i) x[i] = src[(size_t)(lane + 64 * i) * 512];

    fft512_wave<1>(x, lane, scratch[wid]);

#pragma unroll
    for (int i = 0; i < 8; ++i) {
        int n1 = lane + 64 * i;
        tile[0][wid][n1 ^ (wid * 8)] = x[i].x;        // XOR-swizzled: conflict-free both sides
        tile[1][wid][n1 ^ (wid * 8)] = x[i].y;
    }
    __syncthreads();

    float* o0 = out + (size_t)(2 * seq) * L;
    float* o1 = out + (size_t)(2 * seq + 1) * L;
#pragma unroll
    for (int it = 0; it < 2; ++it) {
        int n1 = it * 256 + threadIdx.x;
        int nbase = (n1 << 9) + n2b;
        float v0[4], v1[4];
#pragma unroll
        for (int j = 0; j < 4; ++j) {
            v0[j] = tile[0][j][n1 ^ (j * 8)];
            v1[j] = tile[1][j][n1 ^ (j * 8)];
        }
        if (nbase + 3 < L) {                          // 8B-aligned float2 stores
            *(float2*)(o0 + nbase)     = make_float2(v0[0], v0[1]);
            *(float2*)(o0 + nbase + 2) = make_float2(v0[2], v0[3]);
            *(float2*)(o1 + nbase)     = make_float2(v1[0], v1[1]);
            *(float2*)(o1 + nbase + 2) = make_float2(v1[2], v1[3]);
        } else {
#pragma unroll
            for (int j = 0; j < 4; ++j)
                if (nbase + j < L) { o0[nbase + j] = v0[j]; o1[nbase + j] = v1[j]; }
        }
    }
}

extern "C" void kernel_launch(void* const* d_in, const int* in_sizes, int n_in,
                              void* d_out, int out_size, void* d_ws, size_t ws_size,
                              hipStream_t stream) {
    const float* audio = (const float*)d_in[0];   // (1, 4, T) f32
    const float* rir   = (const float*)d_in[1];   // (T,) f32
    float* out = (float*)d_out;                   // (1, 4, 2T-1) f32
    int L = out_size / 4;                         // 262143

    float2* S = (float2*)d_ws;                    // 3*N complex
    float2* D = S + 3 * NTOT;                     // 2*N complex

    k1_cols<<<384, 256, 0, stream>>>(audio, rir, S);
    k2_rows<<<512, 192, 0, stream>>>(S, D);
    k3_cols<<<256, 256, 0, stream>>>(D, out, L);
}

// Round 4
// 30.691 us; speedup vs baseline: 2.7611x; 1.0453x over previous
//
#include <hip/hip_runtime.h>

// FFT convolution via N = 2^18 = 64 x 4096 Cooley-Tukey.
//   n = 4096*n1 + n2 (n1 in [0,64)), k = k1 + 64*k2.
// KA: per-lane in-register 64-pt FFT over n1 (+ twiddle W_N^{-n2 k1})  -> A1[seq][k1][n2]
// KB: per-block contiguous 4096-pt FFT over n2 (rir + z), pointwise/N,
//     inverse 4096-pt FFT over k2, twiddle W_N^{+n2 k1}                -> D[z][k1][n2]
// KC: per-lane in-register 64-pt inverse FFT over k1, unpack channels. -> out
// All global loads/stores are lane-consecutive (fully coalesced).

#define NTOT 262144
#define TLEN 131072
#define PI2_N    2.3968449808418217e-5f   /* 2*pi / 262144 */
#define PI2_4096 1.5339807878856412e-3f   /* 2*pi / 4096   */
#define PI2_64   9.8174770424681039e-2f   /* 2*pi / 64     */
#define LB(i) ((i) + ((i) >> 3))          /* LDS pad */

__device__ __forceinline__ float2 cadd(float2 a, float2 b) { return make_float2(a.x + b.x, a.y + b.y); }
__device__ __forceinline__ float2 csub(float2 a, float2 b) { return make_float2(a.x - b.x, a.y - b.y); }
__device__ __forceinline__ float2 cmul(float2 a, float2 b) {
    return make_float2(a.x * b.x - a.y * b.y, a.x * b.y + a.y * b.x);
}
__device__ __forceinline__ float2 cexp_(float ang) {
    float s, c;
    __sincosf(ang, &s, &c);
    return make_float2(c, s);
}

template<int SIGN>
__device__ __forceinline__ void dft8(float2 x[8]) {
    const float R2 = 0.70710678118654752f;
    float2 t0 = cadd(x[0], x[4]), t1 = csub(x[0], x[4]);
    float2 t2 = cadd(x[2], x[6]), t3 = csub(x[2], x[6]);
    float2 u0 = cadd(x[1], x[5]), u1 = csub(x[1], x[5]);
    float2 u2 = cadd(x[3], x[7]), u3 = csub(x[3], x[7]);
    float2 it3 = (SIGN > 0) ? make_float2(-t3.y, t3.x) : make_float2(t3.y, -t3.x);
    float2 iu3 = (SIGN > 0) ? make_float2(-u3.y, u3.x) : make_float2(u3.y, -u3.x);
    float2 E0 = cadd(t0, t2), E2 = csub(t0, t2);
    float2 E1 = cadd(t1, it3), E3 = csub(t1, it3);
    float2 O0 = cadd(u0, u2), O2 = csub(u0, u2);
    float2 O1 = cadd(u1, iu3), O3 = csub(u1, iu3);
    float2 iO2 = (SIGN > 0) ? make_float2(-O2.y, O2.x) : make_float2(O2.y, -O2.x);
    float2 w1O1 = (SIGN > 0) ? make_float2(R2 * (O1.x - O1.y), R2 * (O1.y + O1.x))
                             : make_float2(R2 * (O1.x + O1.y), R2 * (O1.y - O1.x));
    float2 w3O3 = (SIGN > 0) ? make_float2(R2 * (-O3.x - O3.y), R2 * (O3.x - O3.y))
                             : make_float2(R2 * (O3.y - O3.x), R2 * (-O3.x - O3.y));
    x[0] = cadd(E0, O0);   x[4] = csub(E0, O0);
    x[1] = cadd(E1, w1O1); x[5] = csub(E1, w1O1);
    x[2] = cadd(E2, iO2);  x[6] = csub(E2, iO2);
    x[3] = cadd(E3, w3O3); x[7] = csub(E3, w3O3);
}

// dft8 with x[4..7] == 0 structurally
template<int SIGN>
__device__ __forceinline__ void dft8z(float2 x[8]) {
    const float R2 = 0.70710678118654752f;
    float2 x0 = x[0], x1 = x[1], x2 = x[2], x3 = x[3];
    float2 rx2 = (SIGN > 0) ? make_float2(-x2.y, x2.x) : make_float2(x2.y, -x2.x);
    float2 rx3 = (SIGN > 0) ? make_float2(-x3.y, x3.x) : make_float2(x3.y, -x3.x);
    float2 E0 = cadd(x0, x2), E2 = csub(x0, x2);
    float2 E1 = cadd(x0, rx2), E3 = csub(x0, rx2);
    float2 O0 = cadd(x1, x3), O2 = csub(x1, x3);
    float2 O1 = cadd(x1, rx3), O3 = csub(x1, rx3);
    float2 iO2 = (SIGN > 0) ? make_float2(-O2.y, O2.x) : make_float2(O2.y, -O2.x);
    float2 w1O1 = (SIGN > 0) ? make_float2(R2 * (O1.x - O1.y), R2 * (O1.y + O1.x))
                             : make_float2(R2 * (O1.x + O1.y), R2 * (O1.y - O1.x));
    float2 w3O3 = (SIGN > 0) ? make_float2(R2 * (-O3.x - O3.y), R2 * (O3.x - O3.y))
                             : make_float2(R2 * (O3.y - O3.x), R2 * (-O3.x - O3.y));
    x[0] = cadd(E0, O0);   x[4] = csub(E0, O0);
    x[1] = cadd(E1, w1O1); x[5] = csub(E1, w1O1);
    x[2] = cadd(E2, iO2);  x[6] = csub(E2, iO2);
    x[3] = cadd(E3, w3O3); x[7] = csub(E3, w3O3);
}

template<int SIGN>
__device__ __forceinline__ void twbase(float2 x[8], int base, float unit) {
#pragma unroll
    for (int i = 1; i < 8; ++i) {
        float ang = unit * (float)(base * i);
        x[i] = cmul(x[i], cexp_((SIGN < 0) ? -ang : ang));
    }
}

// In-register 64-pt FFT, radix-8 x radix-8, in-place.
// REVIN=false: natural input -> phys reg r holds X[rev8(r)].
// REVIN=true : phys reg r holds input[rev8(r)] -> natural output.
// HZ: logical inputs [32..63] are zero (only REVIN=false).
template<int SIGN, bool REVIN, bool HZ = false>
__device__ __forceinline__ void fft64_reg(float2 x[64]) {
#pragma unroll
    for (int t = 0; t < 8; ++t) {
        float2 g[8];
#pragma unroll
        for (int i = 0; i < 8; ++i) g[i] = REVIN ? x[8 * t + i] : x[t + 8 * i];
        if (HZ) dft8z<SIGN>(g); else dft8<SIGN>(g);
        if (t) {
#pragma unroll
            for (int i = 1; i < 8; ++i) {
                float ang = PI2_64 * (float)(t * i);
                g[i] = cmul(g[i], cexp_((SIGN < 0) ? -ang : ang));
            }
        }
#pragma unroll
        for (int i = 0; i < 8; ++i) { if (REVIN) x[8 * t + i] = g[i]; else x[t + 8 * i] = g[i]; }
    }
#pragma unroll
    for (int t = 0; t < 8; ++t) {
        float2 g[8];
#pragma unroll
        for (int i = 0; i < 8; ++i) g[i] = REVIN ? x[t + 8 * i] : x[8 * t + i];
        dft8<SIGN>(g);
#pragma unroll
        for (int i = 0; i < 8; ++i) { if (REVIN) x[t + 8 * i] = g[i]; else x[8 * t + i] = g[i]; }
    }
}

// Block-wide 4096-pt radix-8 Stockham FFT; 512 threads, x[i]=d[t+512i] in/out natural order.
template<int SIGN>
__device__ void fft4096_block(float2 x[8], int t, float2* Lsh) {
    dft8<SIGN>(x);
    twbase<SIGN>(x, t, PI2_4096);
    __syncthreads();                 // WAR vs previous user's reads
#pragma unroll
    for (int i = 0; i < 8; ++i) Lsh[LB(8 * t + i)] = x[i];
    __syncthreads();
    {
        int q = t & 7, p = t >> 3;
#pragma unroll
        for (int i = 0; i < 8; ++i) x[i] = Lsh[LB(q + 8 * p + 512 * i)];
        dft8<SIGN>(x);
        twbase<SIGN>(x, 8 * p, PI2_4096);
        __syncthreads();
#pragma unroll
        for (int i = 0; i < 8; ++i) Lsh[LB(q + 64 * p + 8 * i)] = x[i];
        __syncthreads();
    }
    {
        int q = t & 63, p = t >> 6;
#pragma unroll
        for (int i = 0; i < 8; ++i) x[i] = Lsh[LB(q + 64 * p + 512 * i)];
        dft8<SIGN>(x);
        twbase<SIGN>(x, 64 * p, PI2_4096);
        __syncthreads();
#pragma unroll
        for (int i = 0; i < 8; ++i) Lsh[LB(q + 512 * p + 64 * i)] = x[i];
        __syncthreads();
    }
#pragma unroll
    for (int i = 0; i < 8; ++i) x[i] = Lsh[LB(t + 512 * i)];
    dft8<SIGN>(x);
}

// KA: 192 blocks x 64. seq = bid>>6 (0:z1=c0+ic1, 1:z2=c2+ic3, 2:flipped rir).
__global__ void __launch_bounds__(64, 1) ka(const float* __restrict__ audio,
                                            const float* __restrict__ rir,
                                            float2* __restrict__ A1) {
    int bid = blockIdx.x;
    int seq = bid >> 6;
    int n2 = ((bid & 63) << 6) + threadIdx.x;
    float2 x[64];
    if (seq < 2) {
        const float* c0 = audio + (size_t)(2 * seq) * TLEN;
        const float* c1 = c0 + TLEN;
#pragma unroll
        for (int n1 = 0; n1 < 32; ++n1) {
            int n = (n1 << 12) + n2;
            x[n1] = make_float2(c0[n], c1[n]);
        }
    } else {
#pragma unroll
        for (int n1 = 0; n1 < 32; ++n1) {
            int n = (n1 << 12) + n2;
            x[n1] = make_float2(rir[TLEN - 1 - n], 0.f);
        }
    }
#pragma unroll
    for (int n1 = 32; n1 < 64; ++n1) x[n1] = make_float2(0.f, 0.f);

    fft64_reg<-1, false, true>(x);

    float2* dst = A1 + ((size_t)seq << 18) + n2;
#pragma unroll
    for (int r = 0; r < 64; ++r) {
        int k1 = ((r & 7) << 3) | (r >> 3);   // rev8(r), compile-time
        float2 v = x[r];
        if (k1) v = cmul(v, cexp_(-PI2_N * (float)(n2 * k1)));
        dst[(size_t)k1 << 12] = v;
    }
}

// KB: 128 blocks x 512. z = bid&1, k1 = bid>>1.
__global__ void __launch_bounds__(512) kb(const float2* __restrict__ A1,
                                          float2* __restrict__ D) {
    int z = blockIdx.x & 1;
    int k1 = blockIdx.x >> 1;
    int t = threadIdx.x;
    __shared__ float2 Lsh[4608];   // 4096 + pad

    const float2* az = A1 + ((size_t)z << 18) + ((size_t)k1 << 12);
    const float2* ar = A1 + ((size_t)2 << 18) + ((size_t)k1 << 12);

    float2 zz[8], r8[8];
#pragma unroll
    for (int i = 0; i < 8; ++i) zz[i] = az[t + 512 * i];   // issue early
#pragma unroll
    for (int i = 0; i < 8; ++i) r8[i] = ar[t + 512 * i];

    fft4096_block<-1>(r8, t, Lsh);
    fft4096_block<-1>(zz, t, Lsh);

    const float invN = 3.814697265625e-6f;  // 1/262144
#pragma unroll
    for (int i = 0; i < 8; ++i) {
        float2 y = cmul(zz[i], r8[i]);
        zz[i] = make_float2(y.x * invN, y.y * invN);
    }

    fft4096_block<1>(zz, t, Lsh);

    float2* d = D + ((size_t)z << 18) + ((size_t)k1 << 12) + t;
    if (k1) {
#pragma unroll
        for (int i = 0; i < 8; ++i) {
            int n2 = t + 512 * i;
            d[512 * i] = cmul(zz[i], cexp_(PI2_N * (float)(n2 * k1)));
        }
    } else {
#pragma unroll
        for (int i = 0; i < 8; ++i) d[512 * i] = zz[i];
    }
}

// KC: 128 blocks x 64. z = bid>>6.
__global__ void __launch_bounds__(64, 1) kc(const float2* __restrict__ D,
                                            float* __restrict__ out, int Lout) {
    int bid = blockIdx.x;
    int z = bid >> 6;
    int n2 = ((bid & 63) << 6) + threadIdx.x;

    float2 x[64];
    const float2* src = D + ((size_t)z << 18) + n2;
#pragma unroll
    for (int r = 0; r < 64; ++r) {
        int k1 = ((r & 7) << 3) | (r >> 3);   // load directly into rev layout
        x[r] = src[(size_t)k1 << 12];
    }

    fft64_reg<1, true>(x);                    // natural n1 out

    float* o0 = out + (size_t)(2 * z) * Lout;
    float* o1 = o0 + Lout;
#pragma unroll
    for (int n1 = 0; n1 < 64; ++n1) {
        int n = (n1 << 12) + n2;
        if (n < Lout) { o0[n] = x[n1].x; o1[n] = x[n1].y; }
    }
}

extern "C" void kernel_launch(void* const* d_in, const int* in_sizes, int n_in,
                              void* d_out, int out_size, void* d_ws, size_t ws_size,
                              hipStream_t stream) {
    const float* audio = (const float*)d_in[0];   // (1, 4, T) f32
    const float* rir   = (const float*)d_in[1];   // (T,) f32
    float* out = (float*)d_out;                   // (1, 4, 2T-1) f32
    int Lout = out_size / 4;                      // 262143

    float2* A1 = (float2*)d_ws;                   // 3 * 2^18 complex (6.3 MB)
    float2* D  = A1 + 3 * NTOT;                   // 2 * 2^18 complex (4.2 MB)

    ka<<<192, 64, 0, stream>>>(audio, rir, A1);
    kb<<<128, 512, 0, stream>>>(A1, D);
    kc<<<128, 64, 0, stream>>>(D, out, Lout);
}